// Round 2
// baseline (100.150 us; speedup 1.0000x reference)
//
#include <hip/hip_runtime.h>

// FieldWeightedFactorizationMachine forward — register-lean variant.
// B=32768 rows; F=39 fields; D=64 dims; V=1e6 vocab.
// One 64-lane wave per row: lane = dim d.
// - Row indices loaded once, coalesced (lane i -> idx[i]).
// - readlane -> SGPR index: gathers use scalar base + shared lane offset,
//   bias reads become scalar loads. Frees ~90 VGPRs vs round-0 kernel.

#define FW_B 32768
#define FW_F 39
#define FW_D 64

__global__ __launch_bounds__(256) void fwfm_kernel(
    const int*   __restrict__ x,      // (B, F)
    const float* __restrict__ emb,    // (V, D)
    const float* __restrict__ bias,   // (V, 1)
    const float* __restrict__ W,      // (F, F)
    const float* __restrict__ w0,     // (1,)
    float*       __restrict__ out)    // (B,)
{
    const int wave = threadIdx.x >> 6;            // 0..3
    const int lane = threadIdx.x & 63;            // dim d
    const int row  = blockIdx.x * 4 + wave;
    if (row >= FW_B) return;

    // One coalesced load: lane i (i<39) holds idx[i]. Clamp lanes 39..63
    // to stay in bounds (their values are never readlane'd).
    const int xl   = (lane < FW_F) ? lane : (FW_F - 1);
    const int idxv = x[row * FW_F + xl];

    // Gather embeddings + bias. readlane -> uniform SGPR index:
    //   v[i]   <- global_load_dword v, v_laneoff, s[emb + si*256]
    //   bias   <- scalar load (uniform address)
    float v[FW_F];
    float bsum = 0.0f;
    #pragma unroll
    for (int i = 0; i < FW_F; ++i) {
        const int si = __builtin_amdgcn_readlane(idxv, i);  // SGPR
        const float* __restrict__ p = emb + (size_t)si * FW_D;
        v[i] = p[lane];
        bsum += bias[si];
    }

    // Upper-triangular weighted pairwise products for this lane's dim.
    // W reads are uniform with compile-time offsets -> scalar loads (6KB, sK$).
    float acc = 0.0f;
    #pragma unroll
    for (int i = 0; i < FW_F - 1; ++i) {
        float s = 0.0f;
        #pragma unroll
        for (int j = i + 1; j < FW_F; ++j)
            s = fmaf(W[i * FW_F + j], v[j], s);
        acc = fmaf(v[i], s, acc);
    }

    // Reduce interactions over the 64 dims.
    #pragma unroll
    for (int off = 32; off >= 1; off >>= 1)
        acc += __shfl_xor(acc, off, 64);

    if (lane == 0)
        out[row] = w0[0] + bsum + acc;
}

extern "C" void kernel_launch(void* const* d_in, const int* in_sizes, int n_in,
                              void* d_out, int out_size, void* d_ws, size_t ws_size,
                              hipStream_t stream) {
    const int*   x    = (const int*)  d_in[0];
    const float* emb  = (const float*)d_in[1];
    const float* bias = (const float*)d_in[2];
    const float* W    = (const float*)d_in[3];
    const float* w0   = (const float*)d_in[4];
    float* out        = (float*)d_out;

    const int rows_per_block = 4;                  // 4 waves x 64 lanes
    const int grid = (FW_B + rows_per_block - 1) / rows_per_block;
    fwfm_kernel<<<grid, 256, 0, stream>>>(x, emb, bias, W, w0, out);
}

// Round 3
// 77.371 us; speedup vs baseline: 1.2944x; 1.2944x over previous
//
#include <hip/hip_runtime.h>

// FieldWeightedFactorizationMachine forward — round 2: occupancy-focused.
// B=32768 rows; F=39 fields; D=64 dims; V=1e6 vocab.
// One 64-lane wave per row: lane = dim d.
// - Embedding gathers: uniform idx load + 32-bit zext offset -> saddr-form
//   global_load (1 VGPR/offset instead of 64-bit address pair).
// - Bias: lane i<39 gathers bias[idx_i] itself; summed by the same
//   __shfl_xor reduduction tree as the interactions.
// - __launch_bounds__(256,4): cap 128 VGPR -> 4 waves/SIMD.

#define FW_B 32768
#define FW_F 39
#define FW_D 64

__global__ __launch_bounds__(256, 4) void fwfm_kernel(
    const int*   __restrict__ x,      // (B, F)
    const float* __restrict__ emb,    // (V, D)
    const float* __restrict__ bias,   // (V, 1)
    const float* __restrict__ W,      // (F, F)
    const float* __restrict__ w0,     // (1,)
    float*       __restrict__ out)    // (B,)
{
    const int wave = threadIdx.x >> 6;            // 0..3
    const int lane = threadIdx.x & 63;            // dim d
    const int row  = blockIdx.x * 4 + wave;
    if (row >= FW_B) return;

    // Per-lane bias contribution: lane i (i<39) gathers bias[idx_i].
    // One coalesced idx load + one gather instruction per row.
    float part = 0.0f;
    if (lane < FW_F) {
        const int idxl = x[row * FW_F + lane];
        part = bias[(unsigned)idxl];
    }

    // Gather embeddings: per-i uniform idx load (L1-broadcast), then
    // 32-bit offset so the backend emits saddr-form global_load
    // (SGPR base + 1 VGPR offset). 64 lanes x 4B = one 256B row.
    float v[FW_F];
    #pragma unroll
    for (int i = 0; i < FW_F; ++i) {
        const int si = x[row * FW_F + i];                   // wave-uniform
        const unsigned off = (unsigned)si * (unsigned)FW_D + (unsigned)lane;
        v[i] = emb[off];                                    // zext(32b) + s-base
    }

    // Upper-triangular weighted pairwise products for this lane's dim.
    // W reads are wave-uniform with compile-time offsets -> scalar loads.
    #pragma unroll
    for (int i = 0; i < FW_F - 1; ++i) {
        float s = 0.0f;
        #pragma unroll
        for (int j = i + 1; j < FW_F; ++j)
            s = fmaf(W[i * FW_F + j], v[j], s);
        part = fmaf(v[i], s, part);
    }

    // Reduce (interactions + bias) over the 64 lanes.
    #pragma unroll
    for (int off = 32; off >= 1; off >>= 1)
        part += __shfl_xor(part, off, 64);

    if (lane == 0)
        out[row] = w0[0] + part;
}

extern "C" void kernel_launch(void* const* d_in, const int* in_sizes, int n_in,
                              void* d_out, int out_size, void* d_ws, size_t ws_size,
                              hipStream_t stream) {
    const int*   x    = (const int*)  d_in[0];
    const float* emb  = (const float*)d_in[1];
    const float* bias = (const float*)d_in[2];
    const float* W    = (const float*)d_in[3];
    const float* w0   = (const float*)d_in[4];
    float* out        = (float*)d_out;

    const int rows_per_block = 4;                  // 4 waves x 64 lanes
    const int grid = (FW_B + rows_per_block - 1) / rows_per_block;
    fwfm_kernel<<<grid, 256, 0, stream>>>(x, emb, bias, W, w0, out);
}

// Round 4
// 73.667 us; speedup vs baseline: 1.3595x; 1.0503x over previous
//
#include <hip/hip_runtime.h>

// FieldWeightedFactorizationMachine forward — round 3: non-temporal gathers.
// B=32768 rows; F=39 fields; D=64 dims; V=1e6 vocab.
// One 64-lane wave per row: lane = dim d.
// Embedding stream (327MB, random, zero intra-XCD reuse) marked non-temporal
// so it doesn't thrash the 4MiB/XCD L2; the 4MB bias table then stays
// L2-resident and its 1.28M random 4B reads stop costing 64B HBM lines each.

#define FW_B 32768
#define FW_F 39
#define FW_D 64

__global__ __launch_bounds__(256, 4) void fwfm_kernel(
    const int*   __restrict__ x,      // (B, F)
    const float* __restrict__ emb,    // (V, D)
    const float* __restrict__ bias,   // (V, 1)
    const float* __restrict__ W,      // (F, F)
    const float* __restrict__ w0,     // (1,)
    float*       __restrict__ out)    // (B,)
{
    const int wave = threadIdx.x >> 6;            // 0..3
    const int lane = threadIdx.x & 63;            // dim d
    const int row  = blockIdx.x * 4 + wave;
    if (row >= FW_B) return;

    // Per-lane bias contribution: lane i (i<39) gathers bias[idx_i].
    // Normal (temporal) load — we WANT these cached in L2.
    float part = 0.0f;
    if (lane < FW_F) {
        const int idxl = x[row * FW_F + lane];
        part = bias[(unsigned)idxl];
    }

    // Gather embeddings: uniform idx load, 32-bit zext offset (saddr-form
    // global_load), NON-TEMPORAL so the random stream bypasses L2 allocation.
    float v[FW_F];
    #pragma unroll
    for (int i = 0; i < FW_F; ++i) {
        const int si = x[row * FW_F + i];                   // wave-uniform
        const unsigned off = (unsigned)si * (unsigned)FW_D + (unsigned)lane;
        v[i] = __builtin_nontemporal_load(emb + off);
    }

    // Upper-triangular weighted pairwise products for this lane's dim.
    // W reads are wave-uniform with compile-time offsets -> scalar loads.
    #pragma unroll
    for (int i = 0; i < FW_F - 1; ++i) {
        float s = 0.0f;
        #pragma unroll
        for (int j = i + 1; j < FW_F; ++j)
            s = fmaf(W[i * FW_F + j], v[j], s);
        part = fmaf(v[i], s, part);
    }

    // Reduce (interactions + bias) over the 64 lanes.
    #pragma unroll
    for (int off = 32; off >= 1; off >>= 1)
        part += __shfl_xor(part, off, 64);

    if (lane == 0)
        out[row] = w0[0] + part;
}

extern "C" void kernel_launch(void* const* d_in, const int* in_sizes, int n_in,
                              void* d_out, int out_size, void* d_ws, size_t ws_size,
                              hipStream_t stream) {
    const int*   x    = (const int*)  d_in[0];
    const float* emb  = (const float*)d_in[1];
    const float* bias = (const float*)d_in[2];
    const float* W    = (const float*)d_in[3];
    const float* w0   = (const float*)d_in[4];
    float* out        = (float*)d_out;

    const int rows_per_block = 4;                  // 4 waves x 64 lanes
    const int grid = (FW_B + rows_per_block - 1) / rows_per_block;
    fwfm_kernel<<<grid, 256, 0, stream>>>(x, emb, bias, W, w0, out);
}